// Round 3
// baseline (1219.037 us; speedup 1.0000x reference)
//
#include <hip/hip_runtime.h>
#include <hip/hip_bf16.h>

#define N_ROWS 100000
#define T_DIM 10

// ws layout (bytes)
#define O_H    0ull            // N*128 f32   = 51,200,000
#define O_G    51200000ull     // N*640 bf16  = 128,000,000  [G1(128)|G2(256)|G3(256)]
#define O_PS   179200000ull    // N*16 f32    = 6,400,000
#define O_AL   185600000ull    // N f32       = 400,000
#define O_ACC  186000128ull    // maxbits[16]u32 | sumexp[16]f32 | embs[2560]f32 | wts[16]f32

__device__ __forceinline__ unsigned fmap(float f) {
    unsigned b = __float_as_uint(f);
    return (b & 0x80000000u) ? ~b : (b | 0x80000000u);
}
__device__ __forceinline__ float funmap(unsigned u) {
    unsigned b = (u & 0x80000000u) ? (u & 0x7fffffffu) : ~u;
    return __uint_as_float(b);
}

// K1: H = relu(x @ W1 + b1)   [N,512]x[512,128]
__global__ __launch_bounds__(256) void k1_gemm(const float* __restrict__ x,
        const float* __restrict__ W1, const float* __restrict__ b1,
        float* __restrict__ H) {
    __shared__ float4 xs[16][128];
    int tid = threadIdx.x;
    int n0 = blockIdx.x * 16;
    for (int i = 0; i < 8; ++i) {
        int f = tid + i * 256;
        int row = f >> 7, c4 = f & 127;
        xs[row][c4] = reinterpret_cast<const float4*>(x)[(size_t)(n0 + row) * 128 + c4];
    }
    __syncthreads();
    int l = tid & 127, rg = tid >> 7;
    float acc[8] = {0.f,0.f,0.f,0.f,0.f,0.f,0.f,0.f};
    const float* wp = W1 + l;
    for (int k4 = 0; k4 < 128; ++k4) {
        float w0 = wp[(k4*4+0)*128];
        float w1 = wp[(k4*4+1)*128];
        float w2 = wp[(k4*4+2)*128];
        float w3 = wp[(k4*4+3)*128];
        #pragma unroll
        for (int r = 0; r < 8; ++r) {
            float4 xv = xs[rg*8 + r][k4];
            acc[r] += xv.x*w0 + xv.y*w1 + xv.z*w2 + xv.w*w3;
        }
    }
    float bv = b1[l];
    #pragma unroll
    for (int r = 0; r < 8; ++r) {
        float v = acc[r] + bv;
        H[(size_t)(n0 + rg*8 + r)*128 + l] = v > 0.f ? v : 0.f;
    }
}

// K2: Gall = H @ [Wn | Wp_top | Wp_bot] + [bn | bp | 0]  -> bf16 [N,640]
__global__ __launch_bounds__(256) void k2_gemm(const float* __restrict__ H,
        const float* __restrict__ Wn, const float* __restrict__ bn,
        const float* __restrict__ Wp, const float* __restrict__ bp,
        __hip_bfloat16* __restrict__ G) {
    __shared__ float4 hs[16][32];
    int tid = threadIdx.x;
    int n0 = blockIdx.x * 16;
    for (int i = 0; i < 2; ++i) {
        int f = tid + i * 256;
        int row = f >> 5, c4 = f & 31;
        hs[row][c4] = reinterpret_cast<const float4*>(H)[(size_t)(n0 + row) * 32 + c4];
    }
    __syncthreads();
    int l = tid & 127, rg = tid >> 7;
    for (int ct = 0; ct < 5; ++ct) {
        const float* wbase; int stride; float bv; int ocol;
        if      (ct == 0) { wbase = Wn + l;               stride = 128; bv = bn[l];     ocol = l;     }
        else if (ct == 1) { wbase = Wp + l;               stride = 256; bv = bp[l];     ocol = 128+l; }
        else if (ct == 2) { wbase = Wp + 128 + l;         stride = 256; bv = bp[128+l]; ocol = 256+l; }
        else if (ct == 3) { wbase = Wp + 128*256 + l;     stride = 256; bv = 0.f;       ocol = 384+l; }
        else              { wbase = Wp + 128*256 + 128+l; stride = 256; bv = 0.f;       ocol = 512+l; }
        float acc[8] = {0.f,0.f,0.f,0.f,0.f,0.f,0.f,0.f};
        for (int k4 = 0; k4 < 32; ++k4) {
            float w0 = wbase[(k4*4+0)*stride];
            float w1 = wbase[(k4*4+1)*stride];
            float w2 = wbase[(k4*4+2)*stride];
            float w3 = wbase[(k4*4+3)*stride];
            #pragma unroll
            for (int r = 0; r < 8; ++r) {
                float4 hv = hs[rg*8 + r][k4];
                acc[r] += hv.x*w0 + hv.y*w1 + hv.z*w2 + hv.w*w3;
            }
        }
        #pragma unroll
        for (int r = 0; r < 8; ++r) {
            G[(size_t)(n0 + rg*8 + r)*640 + ocol] = __float2bfloat16(acc[r] + bv);
        }
    }
}

// B: per-row attention: scores, alpha, g = tanh(G2[n]+a0*G3[p]+a1*G3[x]), ps = g.tmpl
__global__ __launch_bounds__(256) void kb_row(const float* __restrict__ H,
        const __hip_bfloat16* __restrict__ G, const float* __restrict__ tmpl,
        float* __restrict__ psg, float* __restrict__ alg) {
    __shared__ float ts[T_DIM * 256];
    int tid = threadIdx.x;
    for (int i = tid; i < T_DIM * 256; i += 256) ts[i] = tmpl[i];
    __syncthreads();
    int w = tid >> 6, l = tid & 63;
    int n = blockIdx.x * 4 + w;
    int prev = (n == 0) ? 1 : n - 1;
    int nxt  = (n == N_ROWS - 1) ? N_ROWS - 2 : n + 1;
    const __hip_bfloat16* gp = G + (size_t)prev * 640;
    const __hip_bfloat16* gx = G + (size_t)nxt * 640;
    const __hip_bfloat16* gn = G + (size_t)n * 640;
    const float* h = H + (size_t)n * 128;
    float h0 = h[l], h1 = h[l + 64];
    float a00 = tanhf(__bfloat162float(gp[l]));
    float a01 = tanhf(__bfloat162float(gp[l + 64]));
    float a10 = tanhf(__bfloat162float(gx[l]));
    float a11 = tanhf(__bfloat162float(gx[l + 64]));
    float s0 = a00 * h0 + a01 * h1;
    float s1 = a10 * h0 + a11 * h1;
    for (int mk = 1; mk < 64; mk <<= 1) { s0 += __shfl_xor(s0, mk, 64); s1 += __shfl_xor(s1, mk, 64); }
    float al0 = 1.f / (1.f + expf(s1 - s0));
    float al1 = 1.f - al0;
    float gv[4];
    #pragma unroll
    for (int m = 0; m < 4; ++m) {
        int j = l + 64 * m;
        float g2  = __bfloat162float(gn[128 + j]);
        float g3p = __bfloat162float(gp[384 + j]);
        float g3x = __bfloat162float(gx[384 + j]);
        gv[m] = tanhf(g2 + al0 * g3p + al1 * g3x);
    }
    float myps = 0.f;
    for (int t = 0; t < T_DIM; ++t) {
        float pt = 0.f;
        #pragma unroll
        for (int m = 0; m < 4; ++m) pt += gv[m] * ts[t * 256 + l + 64 * m];
        for (int mk = 1; mk < 64; mk <<= 1) pt += __shfl_xor(pt, mk, 64);
        if (l == t) myps = pt;
    }
    if (l < T_DIM) psg[(size_t)n * 16 + l] = myps;
    if (l == 0) alg[n] = al0;
}

// C0: per-template max over N
__global__ __launch_bounds__(256) void kc0_max(const float* __restrict__ psg,
        unsigned* __restrict__ maxb) {
    float m[T_DIM];
    #pragma unroll
    for (int t = 0; t < T_DIM; ++t) m[t] = -3.0e38f;
    int gt = blockIdx.x * 256 + threadIdx.x;
    int stride = gridDim.x * 256;
    for (int n = gt; n < N_ROWS; n += stride) {
        #pragma unroll
        for (int t = 0; t < T_DIM; ++t) m[t] = fmaxf(m[t], psg[(size_t)n * 16 + t]);
    }
    #pragma unroll
    for (int t = 0; t < T_DIM; ++t) {
        float v = m[t];
        for (int mk = 1; mk < 64; mk <<= 1) v = fmaxf(v, __shfl_xor(v, mk, 64));
        if ((threadIdx.x & 63) == 0) atomicMax(&maxb[t], fmap(v));
    }
}

// C: sumexp[t] += sum e ; embs_num[t][j] += sum e*Hc[n][j]
__global__ __launch_bounds__(256) void kc_accum(const float* __restrict__ H,
        const float* __restrict__ psg, const float* __restrict__ alg,
        const unsigned* __restrict__ maxb, float* __restrict__ sumexp,
        float* __restrict__ embs) {
    __shared__ float es[32][T_DIM];
    __shared__ float als[32];
    __shared__ float mv[T_DIM];
    int tid = threadIdx.x;
    if (tid < T_DIM) mv[tid] = funmap(maxb[tid]);
    __syncthreads();
    int rpb = (N_ROWS + gridDim.x - 1) / gridDim.x;
    int n0 = blockIdx.x * rpb;
    int n1 = n0 + rpb; if (n1 > N_ROWS) n1 = N_ROWS;
    float acc[T_DIM];
    #pragma unroll
    for (int t = 0; t < T_DIM; ++t) acc[t] = 0.f;
    float sacc = 0.f;
    for (int c0 = n0; c0 < n1; c0 += 32) {
        int cnt = n1 - c0; if (cnt > 32) cnt = 32;
        for (int idx = tid; idx < 32 * T_DIM; idx += 256) {
            int r = idx / T_DIM, t = idx - r * T_DIM;
            float e = 0.f;
            if (r < cnt) e = expf(psg[(size_t)(c0 + r) * 16 + t] - mv[t]);
            es[r][t] = e;
        }
        if (tid < 32) als[tid] = (tid < cnt) ? alg[c0 + tid] : 0.f;
        __syncthreads();
        if (tid < T_DIM) {
            for (int r = 0; r < cnt; ++r) sacc += es[r][tid];
        }
        int j = tid;
        for (int r = 0; r < cnt; ++r) {
            int n = c0 + r;
            float hcj;
            if (j < 128) {
                hcj = H[(size_t)n * 128 + j];
            } else {
                int prev = (n == 0) ? 1 : n - 1;
                int nxt  = (n == N_ROWS - 1) ? N_ROWS - 2 : n + 1;
                float a0 = als[r];
                hcj = a0 * H[(size_t)prev * 128 + (j - 128)] + (1.f - a0) * H[(size_t)nxt * 128 + (j - 128)];
            }
            #pragma unroll
            for (int t = 0; t < T_DIM; ++t) acc[t] += es[r][t] * hcj;
        }
        __syncthreads();
    }
    #pragma unroll
    for (int t = 0; t < T_DIM; ++t) atomicAdd(&embs[t * 256 + tid], acc[t]);
    if (tid < T_DIM) atomicAdd(&sumexp[tid], sacc);
}

// D: single block: embs, gammas, M, Y_prob, Y_hat, wts = gamma/sumexp
__global__ __launch_bounds__(256) void kd_final(
        const float* __restrict__ sumexp, const float* __restrict__ embs_num,
        const float* __restrict__ Wg1, const float* __restrict__ bg1,
        const float* __restrict__ Wg2, const float* __restrict__ bg2,
        const float* __restrict__ Wc, const float* __restrict__ bc,
        float* __restrict__ out, float* __restrict__ wts) {
    __shared__ float embs[T_DIM][256];
    __shared__ float red[8];
    __shared__ float tss[T_DIM];
    __shared__ float gam[T_DIM];
    int tid = threadIdx.x;
    for (int t = 0; t < T_DIM; ++t) embs[t][tid] = embs_num[t * 256 + tid] / sumexp[t];
    __syncthreads();
    for (int t = 0; t < T_DIM; ++t) {
        float partial = 0.f;
        if (tid < 128) {
            float a = bg1[tid];
            for (int jj = 0; jj < 256; ++jj) a += embs[t][jj] * Wg1[jj * 128 + tid];
            partial = tanhf(a) * Wg2[tid];
        }
        float v = partial;
        for (int mk = 1; mk < 64; mk <<= 1) v += __shfl_xor(v, mk, 64);
        if ((tid & 63) == 0 && tid < 128) red[tid >> 6] = v;
        __syncthreads();
        if (tid == 0) tss[t] = red[0] + red[1] + bg2[0];
        __syncthreads();
    }
    if (tid == 0) {
        float mx = tss[0];
        for (int t = 1; t < T_DIM; ++t) mx = fmaxf(mx, tss[t]);
        float s = 0.f;
        for (int t = 0; t < T_DIM; ++t) { gam[t] = expf(tss[t] - mx); s += gam[t]; }
        for (int t = 0; t < T_DIM; ++t) { gam[t] /= s; wts[t] = gam[t] / sumexp[t]; }
    }
    __syncthreads();
    float Mj = 0.f;
    #pragma unroll
    for (int t = 0; t < T_DIM; ++t) Mj += gam[t] * embs[t][tid];
    float p0 = Mj * Wc[tid * 2 + 0];
    float p1 = Mj * Wc[tid * 2 + 1];
    for (int mk = 1; mk < 64; mk <<= 1) { p0 += __shfl_xor(p0, mk, 64); p1 += __shfl_xor(p1, mk, 64); }
    if ((tid & 63) == 0) { red[(tid >> 6) * 2] = p0; red[(tid >> 6) * 2 + 1] = p1; }
    __syncthreads();
    if (tid == 0) {
        float l0 = red[0] + red[2] + red[4] + red[6] + bc[0];
        float l1 = red[1] + red[3] + red[5] + red[7] + bc[1];
        float y0 = 1.f / (1.f + expf(-l0));
        float y1 = 1.f / (1.f + expf(-l1));
        out[0] = y0; out[1] = y1;
        out[2] = (y1 > y0) ? 1.0f : 0.0f;
    }
}

// E: A[n] = sum_t wts[t] * exp(ps[n,t]-max[t])
__global__ __launch_bounds__(256) void ke_A(const float* __restrict__ psg,
        const unsigned* __restrict__ maxb, const float* __restrict__ wts,
        float* __restrict__ outA) {
    __shared__ float wv[T_DIM], mv[T_DIM];
    int tid = threadIdx.x;
    if (tid < T_DIM) { wv[tid] = wts[tid]; mv[tid] = funmap(maxb[tid]); }
    __syncthreads();
    int n = blockIdx.x * 256 + tid;
    if (n < N_ROWS) {
        float a = 0.f;
        const float* p = psg + (size_t)n * 16;
        #pragma unroll
        for (int t = 0; t < T_DIM; ++t) a += wv[t] * expf(p[t] - mv[t]);
        outA[n] = a;
    }
}

extern "C" void kernel_launch(void* const* d_in, const int* in_sizes, int n_in,
                              void* d_out, int out_size, void* d_ws, size_t ws_size,
                              hipStream_t stream) {
    const float* x    = (const float*)d_in[0];
    const float* W1   = (const float*)d_in[1];
    const float* b1   = (const float*)d_in[2];
    const float* Wn   = (const float*)d_in[3];
    const float* bn   = (const float*)d_in[4];
    const float* tmpl = (const float*)d_in[5];
    const float* Wp   = (const float*)d_in[6];
    const float* bp   = (const float*)d_in[7];
    const float* Wg1  = (const float*)d_in[8];
    const float* bg1  = (const float*)d_in[9];
    const float* Wg2  = (const float*)d_in[10];
    const float* bg2  = (const float*)d_in[11];
    const float* Wc   = (const float*)d_in[12];
    const float* bc   = (const float*)d_in[13];

    char* ws = (char*)d_ws;
    float* H            = (float*)(ws + O_H);
    __hip_bfloat16* G   = (__hip_bfloat16*)(ws + O_G);
    float* psg          = (float*)(ws + O_PS);
    float* alg          = (float*)(ws + O_AL);
    unsigned* maxb      = (unsigned*)(ws + O_ACC);
    float* sumexp       = (float*)(ws + O_ACC + 64);
    float* embs         = (float*)(ws + O_ACC + 128);
    float* wts          = (float*)(ws + O_ACC + 128 + 2560 * 4);
    float* out          = (float*)d_out;

    hipMemsetAsync(ws + O_ACC, 0, 128 + 2560 * 4 + 64, stream);
    k1_gemm<<<6250, 256, 0, stream>>>(x, W1, b1, H);
    k2_gemm<<<6250, 256, 0, stream>>>(H, Wn, bn, Wp, bp, G);
    kb_row<<<25000, 256, 0, stream>>>(H, G, tmpl, psg, alg);
    kc0_max<<<128, 256, 0, stream>>>(psg, maxb);
    kc_accum<<<512, 256, 0, stream>>>(H, psg, alg, maxb, sumexp, embs);
    kd_final<<<1, 256, 0, stream>>>(sumexp, embs, Wg1, bg1, Wg2, bg2, Wc, bc, out, wts);
    ke_A<<<391, 256, 0, stream>>>(psg, maxb, wts, out + 3);
}

// Round 6
// 743.116 us; speedup vs baseline: 1.6404x; 1.6404x over previous
//
#include <hip/hip_runtime.h>
#include <hip/hip_bf16.h>

#define N_ROWS 100000
#define T_DIM 10

typedef __attribute__((ext_vector_type(8))) short short8;
typedef __attribute__((ext_vector_type(4))) float f32x4;

// ws layout (bytes)
#define O_H    0ull            // N*128 f32   = 51,200,000
#define O_G    51200000ull     // N*640 bf16  = 128,000,000  [G1(128)|G2(256)|G3(256)]
#define O_PS   179200000ull    // N*16 f32    = 6,400,000
#define O_AL   185600000ull    // N f32       = 400,000
#define O_ACC  186000128ull    // maxbits[16]u32 | sumexp[16]f32 | embs[2560]f32 | wts[16]f32
#define O_W1P  186200064ull    // 512*128 bf16 packed = 131,072 B (16 steps x 8192B, swizzled)
#define O_W2P  186331136ull    // 128*640 bf16 packed = 163,840 B (2 cb x 4 steps x 20480B)
#define O_B2   186494976ull    // 640 f32 = 2,560 B

__device__ __forceinline__ unsigned fmap(float f) {
    unsigned b = __float_as_uint(f);
    return (b & 0x80000000u) ? ~b : (b | 0x80000000u);
}
__device__ __forceinline__ float funmap(unsigned u) {
    unsigned b = (u & 0x80000000u) ? (u & 0x7fffffffu) : ~u;
    return __uint_as_float(b);
}
__device__ __forceinline__ unsigned short f2bf(float f) {
    __hip_bfloat16 h = __float2bfloat16(f);
    return *reinterpret_cast<unsigned short*>(&h);
}

// ---- pack: W1 -> W1pack (swizzled-transposed bf16), [Wn|Wp] -> W2pack, b2all ----
// W1pack: step s (0..15), elem = s*4096 + col*32 + q*8 + e, holds
//   W1[(s*32 + (q ^ ((col>>1)&3))*8 + e)*128 + col]
// W2pack: slice = cb*4+s (0..7), elem = slice*10240 + cl*32 + q*8 + e, holds
//   W2[k = s*32 + (q^((cl>>1)&3))*8 + e][col = cb*320+cl] where
//   W2[k][c] = c<128 ? Wn[k*128+c] : (c<384 ? Wp[k*256+c-128] : Wp[(k+128)*256+c-384])
__global__ __launch_bounds__(256) void k_pack(const float* __restrict__ W1,
        const float* __restrict__ Wn, const float* __restrict__ Wp,
        const float* __restrict__ bn, const float* __restrict__ bp,
        unsigned short* __restrict__ w1p, unsigned short* __restrict__ w2p,
        float* __restrict__ b2) {
    int idx = blockIdx.x * 256 + threadIdx.x;
    if (idx < 65536) {
        int s = idx >> 12, r = idx & 4095;
        int col = r >> 5, q = (r >> 3) & 3, e = r & 7;
        int k = s * 32 + ((q ^ ((col >> 1) & 3)) << 3) + e;
        w1p[idx] = f2bf(W1[k * 128 + col]);
    } else if (idx < 65536 + 81920) {
        int i = idx - 65536;
        int blk = i / 10240, r = i - blk * 10240;  // blk = cb*4+s (0..7), r in [0,10240)
        int cl = r >> 5, q = (r >> 3) & 3, e = r & 7;
        int cb = blk >> 2, s = blk & 3;
        int k = s * 32 + ((q ^ ((cl >> 1) & 3)) << 3) + e;
        int col = cb * 320 + cl;
        float v;
        if (col < 128)      v = Wn[k * 128 + col];
        else if (col < 384) v = Wp[k * 256 + (col - 128)];
        else                v = Wp[(k + 128) * 256 + (col - 384)];
        w2p[i] = f2bf(v);
    } else if (idx < 65536 + 81920 + 640) {
        int c = idx - 65536 - 81920;
        float v;
        if (c < 128)      v = bn[c];
        else if (c < 384) v = bp[c - 128];
        else              v = 0.f;
        b2[c] = v;
    }
}

// ---- K1: H = relu(x @ W1 + b1) via MFMA, tile 128x128, K=512 (16 steps) ----
__global__ __launch_bounds__(256) void k1_mfma(const float* __restrict__ x,
        const unsigned short* __restrict__ w1p, const float* __restrict__ b1,
        float* __restrict__ H) {
    __shared__ unsigned short xs[128 * 32];   // [row][k] chunk-swizzled, 8 KB
    __shared__ unsigned short wsT[128 * 32];  // [col][k] chunk-swizzled, 8 KB
    int tid = threadIdx.x;
    int wave = tid >> 6, lane = tid & 63;
    int n0 = blockIdx.x * 128;
    int l15 = lane & 15, k2 = lane >> 4;

    f32x4 acc[2][8];
    #pragma unroll
    for (int rf = 0; rf < 2; ++rf)
        #pragma unroll
        for (int cf = 0; cf < 8; ++cf) acc[rf][cf] = (f32x4){0.f, 0.f, 0.f, 0.f};

    for (int s = 0; s < 16; ++s) {
        // stage x tile: 128 rows x 32 k, f32 -> bf16, swizzled chunks
        #pragma unroll
        for (int h = 0; h < 2; ++h) {
            int row = h * 64 + (tid >> 2);
            int c = tid & 3;
            int gr = n0 + row; if (gr >= N_ROWS) gr = N_ROWS - 1;
            const float* xp = x + (size_t)gr * 512 + s * 32 + c * 8;
            float4 v0 = *reinterpret_cast<const float4*>(xp);
            float4 v1 = *reinterpret_cast<const float4*>(xp + 4);
            int4 w;
            w.x = f2bf(v0.x) | ((int)f2bf(v0.y) << 16);
            w.y = f2bf(v0.z) | ((int)f2bf(v0.w) << 16);
            w.z = f2bf(v1.x) | ((int)f2bf(v1.y) << 16);
            w.w = f2bf(v1.z) | ((int)f2bf(v1.w) << 16);
            int sc = c ^ ((row >> 1) & 3);
            *reinterpret_cast<int4*>(&xs[row * 32 + sc * 8]) = w;
        }
        // stage W tile: linear 8 KB copy from packed (already swizzled)
        {
            const int4* src = reinterpret_cast<const int4*>(w1p + s * 4096);
            int4* dst = reinterpret_cast<int4*>(wsT);
            dst[tid] = src[tid];
            dst[tid + 256] = src[tid + 256];
        }
        __syncthreads();
        // fragments + MFMA
        short8 a[2], b[8];
        #pragma unroll
        for (int rf = 0; rf < 2; ++rf) {
            int row = wave * 32 + rf * 16 + l15;
            int sc = k2 ^ ((row >> 1) & 3);
            a[rf] = *reinterpret_cast<const short8*>(&xs[row * 32 + sc * 8]);
        }
        #pragma unroll
        for (int cf = 0; cf < 8; ++cf) {
            int col = cf * 16 + l15;
            int sc = k2 ^ ((col >> 1) & 3);
            b[cf] = *reinterpret_cast<const short8*>(&wsT[col * 32 + sc * 8]);
        }
        #pragma unroll
        for (int rf = 0; rf < 2; ++rf)
            #pragma unroll
            for (int cf = 0; cf < 8; ++cf)
                acc[rf][cf] = __builtin_amdgcn_mfma_f32_16x16x32_bf16(a[rf], b[cf], acc[rf][cf], 0, 0, 0);
        __syncthreads();
    }
    // epilogue: bias + relu, store H f32
    #pragma unroll
    for (int cf = 0; cf < 8; ++cf) {
        int col = cf * 16 + l15;
        float bv = b1[col];
        #pragma unroll
        for (int rf = 0; rf < 2; ++rf) {
            #pragma unroll
            for (int i = 0; i < 4; ++i) {
                int row = n0 + wave * 32 + rf * 16 + k2 * 4 + i;
                if (row < N_ROWS) {
                    float v = acc[rf][cf][i] + bv;
                    H[(size_t)row * 128 + col] = v > 0.f ? v : 0.f;
                }
            }
        }
    }
}

// ---- K2: G = H @ W2 + b2 -> bf16, tile 64x320 (cb selects col half), K=128 (4 steps) ----
__global__ __launch_bounds__(256) void k2_mfma(const float* __restrict__ H,
        const unsigned short* __restrict__ w2p, const float* __restrict__ b2,
        __hip_bfloat16* __restrict__ G) {
    __shared__ unsigned short as_[64 * 32];   // 4 KB
    __shared__ unsigned short bs[320 * 32];   // 20 KB
    int tid = threadIdx.x;
    int wave = tid >> 6, lane = tid & 63;
    int bid = blockIdx.x;
    int m = bid >> 1, cb = bid & 1;
    int n0 = m * 64;
    int colbase = cb * 320;
    int l15 = lane & 15, k2 = lane >> 4;

    f32x4 acc[4][5];
    #pragma unroll
    for (int rf = 0; rf < 4; ++rf)
        #pragma unroll
        for (int cf = 0; cf < 5; ++cf) acc[rf][cf] = (f32x4){0.f, 0.f, 0.f, 0.f};

    for (int s = 0; s < 4; ++s) {
        // stage H tile: 64 rows x 32 k, f32 -> bf16, swizzled
        {
            int row = tid >> 2, c = tid & 3;
            int gr = n0 + row; if (gr >= N_ROWS) gr = N_ROWS - 1;
            const float* hp = H + (size_t)gr * 128 + s * 32 + c * 8;
            float4 v0 = *reinterpret_cast<const float4*>(hp);
            float4 v1 = *reinterpret_cast<const float4*>(hp + 4);
            int4 w;
            w.x = f2bf(v0.x) | ((int)f2bf(v0.y) << 16);
            w.y = f2bf(v0.z) | ((int)f2bf(v0.w) << 16);
            w.z = f2bf(v1.x) | ((int)f2bf(v1.y) << 16);
            w.w = f2bf(v1.z) | ((int)f2bf(v1.w) << 16);
            int sc = c ^ ((row >> 1) & 3);
            *reinterpret_cast<int4*>(&as_[row * 32 + sc * 8]) = w;
        }
        // stage W2 slice: linear 20 KB copy (pre-swizzled)
        {
            const int4* src = reinterpret_cast<const int4*>(w2p + (size_t)(cb * 4 + s) * 10240);
            int4* dst = reinterpret_cast<int4*>(bs);
            #pragma unroll
            for (int j = 0; j < 5; ++j) dst[tid + 256 * j] = src[tid + 256 * j];
        }
        __syncthreads();
        short8 a[4], b[5];
        #pragma unroll
        for (int rf = 0; rf < 4; ++rf) {
            int row = rf * 16 + l15;
            int sc = k2 ^ ((row >> 1) & 3);
            a[rf] = *reinterpret_cast<const short8*>(&as_[row * 32 + sc * 8]);
        }
        #pragma unroll
        for (int cf = 0; cf < 5; ++cf) {
            int cl = wave * 80 + cf * 16 + l15;
            int sc = k2 ^ ((cl >> 1) & 3);
            b[cf] = *reinterpret_cast<const short8*>(&bs[cl * 32 + sc * 8]);
        }
        #pragma unroll
        for (int rf = 0; rf < 4; ++rf)
            #pragma unroll
            for (int cf = 0; cf < 5; ++cf)
                acc[rf][cf] = __builtin_amdgcn_mfma_f32_16x16x32_bf16(a[rf], b[cf], acc[rf][cf], 0, 0, 0);
        __syncthreads();
    }
    // epilogue: bias, cvt bf16, store G
    #pragma unroll
    for (int cf = 0; cf < 5; ++cf) {
        int col = colbase + wave * 80 + cf * 16 + l15;
        float bv = b2[col];
        #pragma unroll
        for (int rf = 0; rf < 4; ++rf) {
            #pragma unroll
            for (int i = 0; i < 4; ++i) {
                int row = n0 + rf * 16 + k2 * 4 + i;
                if (row < N_ROWS) {
                    G[(size_t)row * 640 + col] = __float2bfloat16(acc[rf][cf][i] + bv);
                }
            }
        }
    }
}

// B: per-row attention: scores, alpha, g = tanh(G2[n]+a0*G3[p]+a1*G3[x]), ps = g.tmpl
__global__ __launch_bounds__(256) void kb_row(const float* __restrict__ H,
        const __hip_bfloat16* __restrict__ G, const float* __restrict__ tmpl,
        float* __restrict__ psg, float* __restrict__ alg) {
    __shared__ float ts[T_DIM * 256];
    int tid = threadIdx.x;
    for (int i = tid; i < T_DIM * 256; i += 256) ts[i] = tmpl[i];
    __syncthreads();
    int w = tid >> 6, l = tid & 63;
    int n = blockIdx.x * 4 + w;
    int prev = (n == 0) ? 1 : n - 1;
    int nxt  = (n == N_ROWS - 1) ? N_ROWS - 2 : n + 1;
    const __hip_bfloat16* gp = G + (size_t)prev * 640;
    const __hip_bfloat16* gx = G + (size_t)nxt * 640;
    const __hip_bfloat16* gn = G + (size_t)n * 640;
    const float* h = H + (size_t)n * 128;
    float h0 = h[l], h1 = h[l + 64];
    float a00 = tanhf(__bfloat162float(gp[l]));
    float a01 = tanhf(__bfloat162float(gp[l + 64]));
    float a10 = tanhf(__bfloat162float(gx[l]));
    float a11 = tanhf(__bfloat162float(gx[l + 64]));
    float s0 = a00 * h0 + a01 * h1;
    float s1 = a10 * h0 + a11 * h1;
    for (int mk = 1; mk < 64; mk <<= 1) { s0 += __shfl_xor(s0, mk, 64); s1 += __shfl_xor(s1, mk, 64); }
    float al0 = 1.f / (1.f + expf(s1 - s0));
    float al1 = 1.f - al0;
    float gv[4];
    #pragma unroll
    for (int m = 0; m < 4; ++m) {
        int j = l + 64 * m;
        float g2  = __bfloat162float(gn[128 + j]);
        float g3p = __bfloat162float(gp[384 + j]);
        float g3x = __bfloat162float(gx[384 + j]);
        gv[m] = tanhf(g2 + al0 * g3p + al1 * g3x);
    }
    float myps = 0.f;
    for (int t = 0; t < T_DIM; ++t) {
        float pt = 0.f;
        #pragma unroll
        for (int m = 0; m < 4; ++m) pt += gv[m] * ts[t * 256 + l + 64 * m];
        for (int mk = 1; mk < 64; mk <<= 1) pt += __shfl_xor(pt, mk, 64);
        if (l == t) myps = pt;
    }
    if (l < T_DIM) psg[(size_t)n * 16 + l] = myps;
    if (l == 0) alg[n] = al0;
}

// C0: per-template max over N
__global__ __launch_bounds__(256) void kc0_max(const float* __restrict__ psg,
        unsigned* __restrict__ maxb) {
    float m[T_DIM];
    #pragma unroll
    for (int t = 0; t < T_DIM; ++t) m[t] = -3.0e38f;
    int gt = blockIdx.x * 256 + threadIdx.x;
    int stride = gridDim.x * 256;
    for (int n = gt; n < N_ROWS; n += stride) {
        #pragma unroll
        for (int t = 0; t < T_DIM; ++t) m[t] = fmaxf(m[t], psg[(size_t)n * 16 + t]);
    }
    #pragma unroll
    for (int t = 0; t < T_DIM; ++t) {
        float v = m[t];
        for (int mk = 1; mk < 64; mk <<= 1) v = fmaxf(v, __shfl_xor(v, mk, 64));
        if ((threadIdx.x & 63) == 0) atomicMax(&maxb[t], fmap(v));
    }
}

// C: sumexp[t] += sum e ; embs_num[t][j] += sum e*Hc[n][j]
__global__ __launch_bounds__(256) void kc_accum(const float* __restrict__ H,
        const float* __restrict__ psg, const float* __restrict__ alg,
        const unsigned* __restrict__ maxb, float* __restrict__ sumexp,
        float* __restrict__ embs) {
    __shared__ float es[32][T_DIM];
    __shared__ float als[32];
    __shared__ float mv[T_DIM];
    int tid = threadIdx.x;
    if (tid < T_DIM) mv[tid] = funmap(maxb[tid]);
    __syncthreads();
    int rpb = (N_ROWS + gridDim.x - 1) / gridDim.x;
    int n0 = blockIdx.x * rpb;
    int n1 = n0 + rpb; if (n1 > N_ROWS) n1 = N_ROWS;
    float acc[T_DIM];
    #pragma unroll
    for (int t = 0; t < T_DIM; ++t) acc[t] = 0.f;
    float sacc = 0.f;
    for (int c0 = n0; c0 < n1; c0 += 32) {
        int cnt = n1 - c0; if (cnt > 32) cnt = 32;
        for (int idx = tid; idx < 32 * T_DIM; idx += 256) {
            int r = idx / T_DIM, t = idx - r * T_DIM;
            float e = 0.f;
            if (r < cnt) e = expf(psg[(size_t)(c0 + r) * 16 + t] - mv[t]);
            es[r][t] = e;
        }
        if (tid < 32) als[tid] = (tid < cnt) ? alg[c0 + tid] : 0.f;
        __syncthreads();
        if (tid < T_DIM) {
            for (int r = 0; r < cnt; ++r) sacc += es[r][tid];
        }
        int j = tid;
        for (int r = 0; r < cnt; ++r) {
            int n = c0 + r;
            float hcj;
            if (j < 128) {
                hcj = H[(size_t)n * 128 + j];
            } else {
                int prev = (n == 0) ? 1 : n - 1;
                int nxt  = (n == N_ROWS - 1) ? N_ROWS - 2 : n + 1;
                float a0 = als[r];
                hcj = a0 * H[(size_t)prev * 128 + (j - 128)] + (1.f - a0) * H[(size_t)nxt * 128 + (j - 128)];
            }
            #pragma unroll
            for (int t = 0; t < T_DIM; ++t) acc[t] += es[r][t] * hcj;
        }
        __syncthreads();
    }
    #pragma unroll
    for (int t = 0; t < T_DIM; ++t) atomicAdd(&embs[t * 256 + tid], acc[t]);
    if (tid < T_DIM) atomicAdd(&sumexp[tid], sacc);
}

// D: single block: embs, gammas, M, Y_prob, Y_hat, wts = gamma/sumexp
__global__ __launch_bounds__(256) void kd_final(
        const float* __restrict__ sumexp, const float* __restrict__ embs_num,
        const float* __restrict__ Wg1, const float* __restrict__ bg1,
        const float* __restrict__ Wg2, const float* __restrict__ bg2,
        const float* __restrict__ Wc, const float* __restrict__ bc,
        float* __restrict__ out, float* __restrict__ wts) {
    __shared__ float embs[T_DIM][256];
    __shared__ float red[8];
    __shared__ float tss[T_DIM];
    __shared__ float gam[T_DIM];
    int tid = threadIdx.x;
    for (int t = 0; t < T_DIM; ++t) embs[t][tid] = embs_num[t * 256 + tid] / sumexp[t];
    __syncthreads();
    for (int t = 0; t < T_DIM; ++t) {
        float partial = 0.f;
        if (tid < 128) {
            float a = bg1[tid];
            for (int jj = 0; jj < 256; ++jj) a += embs[t][jj] * Wg1[jj * 128 + tid];
            partial = tanhf(a) * Wg2[tid];
        }
        float v = partial;
        for (int mk = 1; mk < 64; mk <<= 1) v += __shfl_xor(v, mk, 64);
        if ((tid & 63) == 0 && tid < 128) red[tid >> 6] = v;
        __syncthreads();
        if (tid == 0) tss[t] = red[0] + red[1] + bg2[0];
        __syncthreads();
    }
    if (tid == 0) {
        float mx = tss[0];
        for (int t = 1; t < T_DIM; ++t) mx = fmaxf(mx, tss[t]);
        float s = 0.f;
        for (int t = 0; t < T_DIM; ++t) { gam[t] = expf(tss[t] - mx); s += gam[t]; }
        for (int t = 0; t < T_DIM; ++t) { gam[t] /= s; wts[t] = gam[t] / sumexp[t]; }
    }
    __syncthreads();
    float Mj = 0.f;
    #pragma unroll
    for (int t = 0; t < T_DIM; ++t) Mj += gam[t] * embs[t][tid];
    float p0 = Mj * Wc[tid * 2 + 0];
    float p1 = Mj * Wc[tid * 2 + 1];
    for (int mk = 1; mk < 64; mk <<= 1) { p0 += __shfl_xor(p0, mk, 64); p1 += __shfl_xor(p1, mk, 64); }
    if ((tid & 63) == 0) { red[(tid >> 6) * 2] = p0; red[(tid >> 6) * 2 + 1] = p1; }
    __syncthreads();
    if (tid == 0) {
        float l0 = red[0] + red[2] + red[4] + red[6] + bc[0];
        float l1 = red[1] + red[3] + red[5] + red[7] + bc[1];
        float y0 = 1.f / (1.f + expf(-l0));
        float y1 = 1.f / (1.f + expf(-l1));
        out[0] = y0; out[1] = y1;
        out[2] = (y1 > y0) ? 1.0f : 0.0f;
    }
}

// E: A[n] = sum_t wts[t] * exp(ps[n,t]-max[t])
__global__ __launch_bounds__(256) void ke_A(const float* __restrict__ psg,
        const unsigned* __restrict__ maxb, const float* __restrict__ wts,
        float* __restrict__ outA) {
    __shared__ float wv[T_DIM], mv[T_DIM];
    int tid = threadIdx.x;
    if (tid < T_DIM) { wv[tid] = wts[tid]; mv[tid] = funmap(maxb[tid]); }
    __syncthreads();
    int n = blockIdx.x * 256 + tid;
    if (n < N_ROWS) {
        float a = 0.f;
        const float* p = psg + (size_t)n * 16;
        #pragma unroll
        for (int t = 0; t < T_DIM; ++t) a += wv[t] * expf(p[t] - mv[t]);
        outA[n] = a;
    }
}

extern "C" void kernel_launch(void* const* d_in, const int* in_sizes, int n_in,
                              void* d_out, int out_size, void* d_ws, size_t ws_size,
                              hipStream_t stream) {
    const float* x    = (const float*)d_in[0];
    const float* W1   = (const float*)d_in[1];
    const float* b1   = (const float*)d_in[2];
    const float* Wn   = (const float*)d_in[3];
    const float* bn   = (const float*)d_in[4];
    const float* tmpl = (const float*)d_in[5];
    const float* Wp   = (const float*)d_in[6];
    const float* bp   = (const float*)d_in[7];
    const float* Wg1  = (const float*)d_in[8];
    const float* bg1  = (const float*)d_in[9];
    const float* Wg2  = (const float*)d_in[10];
    const float* bg2  = (const float*)d_in[11];
    const float* Wc   = (const float*)d_in[12];
    const float* bc   = (const float*)d_in[13];

    char* ws = (char*)d_ws;
    float* H            = (float*)(ws + O_H);
    __hip_bfloat16* G   = (__hip_bfloat16*)(ws + O_G);
    float* psg          = (float*)(ws + O_PS);
    float* alg          = (float*)(ws + O_AL);
    unsigned* maxb      = (unsigned*)(ws + O_ACC);
    float* sumexp       = (float*)(ws + O_ACC + 64);
    float* embs         = (float*)(ws + O_ACC + 128);
    float* wts          = (float*)(ws + O_ACC + 128 + 2560 * 4);
    unsigned short* w1p = (unsigned short*)(ws + O_W1P);
    unsigned short* w2p = (unsigned short*)(ws + O_W2P);
    float* b2all        = (float*)(ws + O_B2);
    float* out          = (float*)d_out;

    hipMemsetAsync(ws + O_ACC, 0, 128 + 2560 * 4 + 64, stream);
    k_pack<<<579, 256, 0, stream>>>(W1, Wn, Wp, bn, bp, w1p, w2p, b2all);
    k1_mfma<<<782, 256, 0, stream>>>(x, w1p, b1, H);
    k2_mfma<<<3126, 256, 0, stream>>>(H, w2p, b2all, G);
    kb_row<<<25000, 256, 0, stream>>>(H, G, tmpl, psg, alg);
    kc0_max<<<128, 256, 0, stream>>>(psg, maxb);
    kc_accum<<<512, 256, 0, stream>>>(H, psg, alg, maxb, sumexp, embs);
    kd_final<<<1, 256, 0, stream>>>(sumexp, embs, Wg1, bg1, Wg2, bg2, Wc, bc, out, wts);
    ke_A<<<391, 256, 0, stream>>>(psg, maxb, wts, out + 3);
}